// Round 6
// baseline (109.387 us; speedup 1.0000x reference)
//
#include <hip/hip_runtime.h>
#include <hip/hip_bf16.h>

// Curvature stencil, (16,1024,1024) fp32, reflect boundary.
// R6 = R5 with 16-row tiles (was 8):
//   - Each thread: 18 row float4 loads -> 16 output rows. VMEM per output
//     float4: 2.125; vertical halo amplification 1.125x.
//   - Edge neighbors via wave shuffles; lanes 0/63 scalar-load fallback.
//   - Non-temporal output stores.
//   - Grid 1024 blocks; XCD swizzle keeps each XCD on a contiguous slab.

#define Wdim 1024
#define Hdim 1024
#define EPSf 1e-16f
#define TR 16                        // tile rows

typedef float v4f __attribute__((ext_vector_type(4)));

__global__ __launch_bounds__(256) void curv_kernel(const float* __restrict__ u,
                                                   float* __restrict__ out) {
    // 1024 blocks: XCD (idx%8) gets 128 contiguous logical block-rows
    int blk = ((blockIdx.x & 7) << 7) | (blockIdx.x >> 3);
    int q  = threadIdx.x;            // float4 column, 0..255
    int w0 = q << 2;
    int rowBlk = blk & 63;           // 64 row-blocks of 16 rows per image
    int b      = blk >> 6;
    int r0     = rowBlk << 4;

    const float* base = u + ((size_t)b << 20);

    int rIdx[TR + 2];
    rIdx[0] = (r0 == 0) ? 1 : r0 - 1;                    // reflect(-1)=1
#pragma unroll
    for (int k = 1; k <= TR; ++k) rIdx[k] = r0 + k - 1;
    rIdx[TR + 1] = (r0 + TR == Hdim) ? Hdim - 2 : r0 + TR;  // reflect(H)=H-2

    v4f R[TR + 2];
#pragma unroll
    for (int k = 0; k < TR + 2; ++k)
        R[k] = ((const v4f*)(base + (size_t)rIdx[k] * Wdim))[q];

    // Neighbors via shuffle: Lv[k] = lane-1's R[k].w, Rv[k] = lane+1's R[k].x
    float Lv[TR + 2], Rv[TR + 2];
#pragma unroll
    for (int k = 1; k < TR + 2; ++k) Lv[k] = __shfl_up(R[k].w, 1);
#pragma unroll
    for (int k = 0; k < TR + 1; ++k) Rv[k] = __shfl_down(R[k].x, 1);

    int lane = threadIdx.x & 63;
    if (lane == 0) {
        if (w0 == 0) {               // image left edge: reflect(-1)=1 -> .y
#pragma unroll
            for (int k = 1; k < TR + 2; ++k) Lv[k] = R[k].y;
        } else {                     // wave boundary mid-row: scalar load
#pragma unroll
            for (int k = 1; k < TR + 2; ++k)
                Lv[k] = base[(size_t)rIdx[k] * Wdim + w0 - 1];
        }
    }
    if (lane == 63) {
        if (w0 + 4 == Wdim) {        // image right edge: reflect(W)=W-2 -> .z
#pragma unroll
            for (int k = 0; k < TR + 1; ++k) Rv[k] = R[k].z;
        } else {
#pragma unroll
            for (int k = 0; k < TR + 1; ++k)
                Rv[k] = base[(size_t)rIdx[k] * Wdim + w0 + 4];
        }
    }

    size_t obase = ((size_t)b << 20) + (size_t)r0 * Wdim;
#pragma unroll
    for (int j = 0; j < TR; ++j) {
        v4f C = R[1 + j];
        v4f M = R[j];
        v4f P = R[2 + j];
        float c[6] = {Lv[1 + j], C.x, C.y, C.z, C.w, Rv[1 + j]};
        float m[5] = {M.x, M.y, M.z, M.w, Rv[j]};
        float p[5] = {Lv[2 + j], P.x, P.y, P.z, P.w};

        v4f o;
#pragma unroll
        for (int i = 0; i < 4; ++i) {
            float cc   = c[i + 1];
            float cyp  = c[i + 2];
            float cym  = c[i];
            float mm   = m[i];
            float myp  = m[i + 1];
            float pp   = p[i + 1];
            float pym  = p[i];

            float dxf  = pp  - cc;
            float dxb  = cc  - mm;
            float dyf  = cyp - cc;
            float dyb  = cc  - cym;
            float dsbf = myp - mm;
            float dslf = pym - cym;

            float invF = rsqrtf(dxf * dxf + dyf * dyf + EPSf);
            float invG = rsqrtf(dxb * dxb + dsbf * dsbf + EPSf);
            float invH = rsqrtf(dslf * dslf + dyb * dyb + EPSf);

            o[i] = (dxf + dyf) * invF - dxb * invG - dyb * invH;
        }
        __builtin_nontemporal_store(o, (v4f*)(out + obase + (size_t)j * Wdim) + q);
    }
}

extern "C" void kernel_launch(void* const* d_in, const int* in_sizes, int n_in,
                              void* d_out, int out_size, void* d_ws, size_t ws_size,
                              hipStream_t stream) {
    const float* u = (const float*)d_in[0];
    float* out = (float*)d_out;
    // 16 images * 64 row-blocks = 1024 blocks of 256 threads
    curv_kernel<<<1024, 256, 0, stream>>>(u, out);
}

// Round 7
// 105.514 us; speedup vs baseline: 1.0367x; 1.0367x over previous
//
#include <hip/hip_runtime.h>
#include <hip/hip_bf16.h>

// Curvature stencil, (16,1024,1024) fp32, reflect boundary.
// R7 = revert to R5 (TR=8), the measured best:
//   - TR=16 (R6) regressed: ~170 VGPRs -> ~3 waves/SIMD and only 4 blocks/CU;
//     the extra VMEM amortization (2.25->2.125 instrs/float4) didn't pay for
//     the lost latency-hiding. TR=8 is the sweet spot.
//   - Each thread: 10 row float4 loads -> 8 output rows; shuffles for l/r
//     neighbors (lanes 0/63 scalar fallback); non-temporal output stores;
//     XCD swizzle keeps each XCD on a contiguous slab of rows.
//   - Kernel ~25 us = 141 MB / 25 us = 5.6 TB/s, ~89% of the 6.3 TB/s
//     achievable ceiling (demonstrated by the harness's own 262 MB memsets).

#define Wdim 1024
#define Hdim 1024
#define EPSf 1e-16f
#define TR 8                         // tile rows

typedef float v4f __attribute__((ext_vector_type(4)));

__global__ __launch_bounds__(256) void curv_kernel(const float* __restrict__ u,
                                                   float* __restrict__ out) {
    int blk = ((blockIdx.x & 7) << 8) | (blockIdx.x >> 3);
    int q  = threadIdx.x;            // float4 column, 0..255
    int w0 = q << 2;
    int rowBlk = blk & 127;          // 128 row-blocks of 8 rows per image
    int b      = blk >> 7;
    int r0     = rowBlk << 3;

    const float* base = u + ((size_t)b << 20);

    int rIdx[TR + 2];
    rIdx[0] = (r0 == 0) ? 1 : r0 - 1;                    // reflect(-1)=1
#pragma unroll
    for (int k = 1; k <= TR; ++k) rIdx[k] = r0 + k - 1;
    rIdx[TR + 1] = (r0 + TR == Hdim) ? Hdim - 2 : r0 + TR;  // reflect(H)=H-2

    v4f R[TR + 2];
#pragma unroll
    for (int k = 0; k < TR + 2; ++k)
        R[k] = ((const v4f*)(base + (size_t)rIdx[k] * Wdim))[q];

    // Neighbors via shuffle: Lv[k] = lane-1's R[k].w, Rv[k] = lane+1's R[k].x
    float Lv[TR + 2], Rv[TR + 2];
#pragma unroll
    for (int k = 1; k < TR + 2; ++k) Lv[k] = __shfl_up(R[k].w, 1);
#pragma unroll
    for (int k = 0; k < TR + 1; ++k) Rv[k] = __shfl_down(R[k].x, 1);

    int lane = threadIdx.x & 63;
    if (lane == 0) {
        if (w0 == 0) {               // image left edge: reflect(-1)=1 -> .y
#pragma unroll
            for (int k = 1; k < TR + 2; ++k) Lv[k] = R[k].y;
        } else {                     // wave boundary mid-row: scalar load
#pragma unroll
            for (int k = 1; k < TR + 2; ++k)
                Lv[k] = base[(size_t)rIdx[k] * Wdim + w0 - 1];
        }
    }
    if (lane == 63) {
        if (w0 + 4 == Wdim) {        // image right edge: reflect(W)=W-2 -> .z
#pragma unroll
            for (int k = 0; k < TR + 1; ++k) Rv[k] = R[k].z;
        } else {
#pragma unroll
            for (int k = 0; k < TR + 1; ++k)
                Rv[k] = base[(size_t)rIdx[k] * Wdim + w0 + 4];
        }
    }

    size_t obase = ((size_t)b << 20) + (size_t)r0 * Wdim;
#pragma unroll
    for (int j = 0; j < TR; ++j) {
        v4f C = R[1 + j];
        v4f M = R[j];
        v4f P = R[2 + j];
        float c[6] = {Lv[1 + j], C.x, C.y, C.z, C.w, Rv[1 + j]};
        float m[5] = {M.x, M.y, M.z, M.w, Rv[j]};
        float p[5] = {Lv[2 + j], P.x, P.y, P.z, P.w};

        v4f o;
#pragma unroll
        for (int i = 0; i < 4; ++i) {
            float cc   = c[i + 1];
            float cyp  = c[i + 2];
            float cym  = c[i];
            float mm   = m[i];
            float myp  = m[i + 1];
            float pp   = p[i + 1];
            float pym  = p[i];

            float dxf  = pp  - cc;
            float dxb  = cc  - mm;
            float dyf  = cyp - cc;
            float dyb  = cc  - cym;
            float dsbf = myp - mm;
            float dslf = pym - cym;

            float invF = rsqrtf(dxf * dxf + dyf * dyf + EPSf);
            float invG = rsqrtf(dxb * dxb + dsbf * dsbf + EPSf);
            float invH = rsqrtf(dslf * dslf + dyb * dyb + EPSf);

            o[i] = (dxf + dyf) * invF - dxb * invG - dyb * invH;
        }
        __builtin_nontemporal_store(o, (v4f*)(out + obase + (size_t)j * Wdim) + q);
    }
}

extern "C" void kernel_launch(void* const* d_in, const int* in_sizes, int n_in,
                              void* d_out, int out_size, void* d_ws, size_t ws_size,
                              hipStream_t stream) {
    const float* u = (const float*)d_in[0];
    float* out = (float*)d_out;
    // 16 images * 128 row-blocks = 2048 blocks of 256 threads
    curv_kernel<<<2048, 256, 0, stream>>>(u, out);
}